// Round 1
// baseline (633.993 us; speedup 1.0000x reference)
//
#include <hip/hip_runtime.h>
#include <math.h>

// AugmentPipe: flip -> affine(rot/scale/trans) bilinear-reflect sample ->
// brightness -> contrast -> saturation -> cutout(noise). One fused pass.
// B=64, C=3, H=W=512, float32 in/out.
//
// R2 -> R3: still TA-bound (72 cy/gather-load, HBM 26%, VALU 37%). Change:
// stage each block's source footprint (affine => bounding box of the 4 tile
// corners, <= 1247 floats/channel worst case) into LDS with coalesced row
// loads, then bilinear-gather from LDS (ds_read2_b32 pairs). The reference's
// reflect == clip(v,0,size-1) for v in [-1, 512], and clamping integer taps
// into the staged box reproduces clip semantics exactly (clamped taps
// coincide, so the lerp weight multiplies zero). Blocks whose corners leave
// [-0.9, 511.9] (true reflection) take the old global-gather path,
// branch-uniform per block (~10-20% of blocks).

constexpr int Bn = 64;
constexpr int Cn = 3;
constexpr int Hn = 512;
constexpr int Wn = 512;
constexpr float TRANSLATE_STD = 0.125f;
constexpr float SCALE_STD = 0.2f;
constexpr int CUT_H = 256; // int(512*0.5)
constexpr int CUT_W = 256;

// Worst-case staged footprint per channel:
// (dx+3)(dy+3), dx=1.2*(512/511)*(31|c|+7|s|), dy likewise swapped
// max at 45deg, sc=1.2: ~1247 floats. Guarded at runtime anyway.
constexpr int LDS_CAP = 1280;

typedef float f2v __attribute__((ext_vector_type(2)));

__device__ __forceinline__ f2v load2(const float* p) {
    // 8B load with only 4B alignment guarantee; gfx950 supports unaligned
    // global access so this emits global_load_dwordx2.
    f2v r;
    __builtin_memcpy(&r, p, 8);
    return r;
}

__device__ __forceinline__ float reflect_coord(float v, float size) {
    v = fabsf(v + 0.5f);
    v = fmodf(v, 2.0f * size);
    v = fminf(v, 2.0f * size - v);
    return fminf(fmaxf(v - 0.5f, 0.0f), size - 1.0f);
}

__global__ __launch_bounds__(256) void augment_kernel(
    const float* __restrict__ images,
    const float* __restrict__ u_angle,
    const float* __restrict__ u_scale,
    const float* __restrict__ u_trans,
    const float* __restrict__ u_bright,
    const float* __restrict__ u_contrast,
    const float* __restrict__ u_sat,
    const float* __restrict__ noise,
    const int* __restrict__ m_flip,
    const int* __restrict__ m_rot,
    const int* __restrict__ m_scale,
    const int* __restrict__ m_trans,
    const int* __restrict__ m_bright,
    const int* __restrict__ m_contrast,
    const int* __restrict__ m_sat,
    const int* __restrict__ m_cut,
    const int* __restrict__ y0p,
    const int* __restrict__ x0p,
    float* __restrict__ out)
{
    __shared__ float lds[Cn * LDS_CAP];   // 15360 B -> still 8 blocks/CU

    const int x = blockIdx.x * 32 + threadIdx.x;
    const int y = blockIdx.y * 8 + threadIdx.y;
    const int b = blockIdx.z;

    // Per-batch params — blockIdx.z-uniform => scalar loads.
    const float angle = (m_rot[b] > 0) ? (u_angle[b] * 2.0f - 1.0f) * 3.14159265358979323846f : 0.0f;
    const float sc    = (m_scale[b] > 0) ? (u_scale[b] * 2.0f - 1.0f) * SCALE_STD + 1.0f : 1.0f;
    const float tr    = (m_trans[b] > 0) ? (u_trans[b] * 2.0f - 1.0f) * TRANSLATE_STD : 0.0f;
    const float bb    = (m_bright[b] > 0) ? u_bright[b] * 0.2f : 0.0f;
    const float cc    = (m_contrast[b] > 0) ? u_contrast[b] + 0.5f : 1.0f;
    const float ss    = (m_sat[b] > 0) ? u_sat[b] * 2.0f : 1.0f;
    const bool  flip  = m_flip[b] > 0;
    const bool  docut = m_cut[b] > 0;
    const int   cy0   = y0p[b];
    const int   cx0   = x0p[b];

    float saf, caf;
    __sincosf(angle, &saf, &caf);

    // Source coordinate (same fp ops for pixels and corners so extremes match
    // per-pixel values to ~1 ulp; the 0.1 px slack in the staged test covers it).
    auto coord = [&](float fx, float fy, float& oxx, float& oyy) {
        const float gx0 = -1.0f + (2.0f / 511.0f) * fx;
        const float gy0 = -1.0f + (2.0f / 511.0f) * fy;
        const float gx = sc * (caf * gx0 - saf * gy0) + tr;
        const float gy = sc * (saf * gx0 + caf * gy0) + tr;
        oxx = ((gx + 1.0f) * (float)Wn - 1.0f) * 0.5f;
        oyy = ((gy + 1.0f) * (float)Hn - 1.0f) * 0.5f;
    };

    float xx, yy;
    coord((float)x, (float)y, xx, yy);

    // Block-uniform staged-path test from the 4 tile corners (affine => exact).
    const float tx0 = (float)(blockIdx.x * 32);
    const float tx1 = tx0 + 31.0f;
    const float ty0 = (float)(blockIdx.y * 8);
    const float ty1 = ty0 + 7.0f;
    float cxx0, cyy0, cxx1, cyy1, cxx2, cyy2, cxx3, cyy3;
    coord(tx0, ty0, cxx0, cyy0);
    coord(tx1, ty0, cxx1, cyy1);
    coord(tx0, ty1, cxx2, cyy2);
    coord(tx1, ty1, cxx3, cyy3);
    const float minxx = fminf(fminf(cxx0, cxx1), fminf(cxx2, cxx3));
    const float maxxx = fmaxf(fmaxf(cxx0, cxx1), fmaxf(cxx2, cxx3));
    const float minyy = fminf(fminf(cyy0, cyy1), fminf(cyy2, cyy3));
    const float maxyy = fmaxf(fmaxf(cyy0, cyy1), fmaxf(cyy2, cyy3));

    // reflect == clip for coords in [-1.0, 512.0]; 0.1 px safety margin.
    bool staged = (minxx >= -0.9f) && (maxxx <= 511.9f) &&
                  (minyy >= -0.9f) && (maxyy <= 511.9f);

    int x_lo = 0, x_hi = 1, y_lo = 0, y_hi = 1, fw = 2, fh = 2;
    if (staged) {
        x_lo = max(0, (int)floorf(minxx));
        x_hi = min(Wn - 1, (int)floorf(maxxx) + 1);
        x_lo = max(0, min(x_lo, x_hi - 1));
        y_lo = max(0, (int)floorf(minyy));
        y_hi = min(Hn - 1, (int)floorf(maxyy) + 1);
        y_lo = max(0, min(y_lo, y_hi - 1));
        fw = x_hi - x_lo + 1;
        fh = y_hi - y_lo + 1;
        if (fw * fh > LDS_CAP) staged = false;   // paranoia guard
    }

    const size_t plane = (size_t)Hn * Wn;
    const float* imgb = images + (size_t)b * Cn * plane;

    float vals[Cn];

    if (staged) {
        // ---- Cooperative stage: coalesced row reads, flip folded into the
        // source column so per-pixel lookups use unflipped indices.
        #pragma unroll
        for (int c = 0; c < Cn; ++c) {
            const float* src = imgb + (size_t)c * plane;
            float* dst = &lds[c * LDS_CAP];
            for (int ry = threadIdx.y; ry < fh; ry += 8) {
                const float* rowp = src + (size_t)(y_lo + ry) * Wn;
                for (int rx = threadIdx.x; rx < fw; rx += 32) {
                    const int gxc = x_lo + rx;
                    dst[ry * fw + rx] = rowp[flip ? (Wn - 1 - gxc) : gxc];
                }
            }
        }
        __syncthreads();

        // ---- Bilinear from LDS. Taps clamped into the staged box reproduce
        // the reference clip semantics exactly (clamped => taps coincide =>
        // the out-of-range lerp weight multiplies zero).
        const float x0f = floorf(xx);
        const float y0f = floorf(yy);
        const float wx = xx - x0f;
        const float wy = yy - y0f;
        const int x0i = (int)x0f;
        const int y0i = (int)y0f;

        const int xa = min(max(x0i, x_lo), x_hi);
        const int xb = min(max(x0i + 1, x_lo), x_hi);
        const int pb = min(xa, x_hi - 1);          // pair base, >= x_lo
        const bool s0 = (xa != pb);
        const bool s1 = (xb != pb);
        const int ya = min(max(y0i, y_lo), y_hi) - y_lo;
        const int yb = min(max(y0i + 1, y_lo), y_hi) - y_lo;
        const int col = pb - x_lo;
        const int off0 = ya * fw + col;
        const int off1 = yb * fw + col;

        #pragma unroll
        for (int c = 0; c < Cn; ++c) {
            const float* ch = &lds[c * LDS_CAP];
            const float t0x = ch[off0], t0y = ch[off0 + 1];   // ds_read2_b32
            const float t1x = ch[off1], t1y = ch[off1 + 1];
            const float v00 = s0 ? t0y : t0x;
            const float v01 = s1 ? t0y : t0x;
            const float v10 = s0 ? t1y : t1x;
            const float v11 = s1 ? t1y : t1x;
            const float top = v00 + wx * (v01 - v00);
            const float bot = v10 + wx * (v11 - v10);
            float v = top + wy * (bot - top);
            v = fminf(fmaxf(v + bb, -1.0f), 1.0f);   // brightness + clip
            v = fminf(fmaxf(v * cc, -1.0f), 1.0f);   // contrast + clip
            vals[c] = v;
        }
    } else {
        // ---- Fallback: direct global gather with true reflect (boundary
        // blocks of transformed batches). Identical to the R2 kernel.
        const float rxx = reflect_coord(xx, (float)Wn);
        const float ryy = reflect_coord(yy, (float)Hn);

        const float x0f = floorf(rxx);
        const float y0f = floorf(ryy);
        const float wx = rxx - x0f;
        const float wy = ryy - y0f;

        int x0i = (int)fminf(fmaxf(x0f, 0.0f), (float)(Wn - 1));
        int x1i = (int)fminf(x0f + 1.0f, (float)(Wn - 1));
        const int y0i = (int)fminf(fmaxf(y0f, 0.0f), (float)(Hn - 1));
        const int y1i = (int)fminf(y0f + 1.0f, (float)(Hn - 1));

        if (flip) { x0i = (Wn - 1) - x0i; x1i = (Wn - 1) - x1i; }

        const int xbase = min(min(x0i, x1i), Wn - 2);
        const bool s0 = (x0i != xbase);
        const bool s1 = (x1i != xbase);

        const int r0 = y0i * Wn + xbase;
        const int r1 = y1i * Wn + xbase;

        #pragma unroll
        for (int c = 0; c < Cn; ++c) {
            const float* p = imgb + (size_t)c * plane;
            const f2v t0 = load2(p + r0);
            const f2v t1 = load2(p + r1);
            const float v00 = s0 ? t0.y : t0.x;
            const float v01 = s1 ? t0.y : t0.x;
            const float v10 = s0 ? t1.y : t1.x;
            const float v11 = s1 ? t1.y : t1.x;
            const float top = v00 + wx * (v01 - v00);
            const float bot = v10 + wx * (v11 - v10);
            float v = top + wy * (bot - top);
            v = fminf(fmaxf(v + bb, -1.0f), 1.0f);
            v = fminf(fmaxf(v * cc, -1.0f), 1.0f);
            vals[c] = v;
        }
    }

    const float gray = (vals[0] + vals[1] + vals[2]) * (1.0f / 3.0f);
    const bool cut = docut && (y >= cy0) && (y < cy0 + CUT_H) && (x >= cx0) && (x < cx0 + CUT_W);

    const size_t base = (size_t)b * Cn * plane + (size_t)y * Wn + (size_t)x;
    #pragma unroll
    for (int c = 0; c < Cn; ++c) {
        float v = gray + ss * (vals[c] - gray);
        v = fminf(fmaxf(v, -1.0f), 1.0f);
        if (cut) v = __builtin_nontemporal_load(&noise[base + c * plane]);
        __builtin_nontemporal_store(v, &out[base + c * plane]);
    }
}

extern "C" void kernel_launch(void* const* d_in, const int* in_sizes, int n_in,
                              void* d_out, int out_size, void* d_ws, size_t ws_size,
                              hipStream_t stream) {
    const float* images     = (const float*)d_in[0];
    const float* u_angle    = (const float*)d_in[1];
    const float* u_scale    = (const float*)d_in[2];
    const float* u_trans    = (const float*)d_in[3];
    const float* u_bright   = (const float*)d_in[4];
    const float* u_contrast = (const float*)d_in[5];
    const float* u_sat      = (const float*)d_in[6];
    const float* noise      = (const float*)d_in[7];
    const int*   m_flip     = (const int*)d_in[8];
    const int*   m_rot      = (const int*)d_in[9];
    const int*   m_scale    = (const int*)d_in[10];
    const int*   m_trans    = (const int*)d_in[11];
    const int*   m_bright   = (const int*)d_in[12];
    const int*   m_contrast = (const int*)d_in[13];
    const int*   m_sat      = (const int*)d_in[14];
    const int*   m_cut      = (const int*)d_in[15];
    const int*   y0p        = (const int*)d_in[16];
    const int*   x0p        = (const int*)d_in[17];
    float* out = (float*)d_out;

    dim3 block(32, 8);
    dim3 grid(Wn / 32, Hn / 8, Bn);
    augment_kernel<<<grid, block, 0, stream>>>(
        images, u_angle, u_scale, u_trans, u_bright, u_contrast, u_sat, noise,
        m_flip, m_rot, m_scale, m_trans, m_bright, m_contrast, m_sat, m_cut,
        y0p, x0p, out);
}

// Round 2
// 589.470 us; speedup vs baseline: 1.0755x; 1.0755x over previous
//
#include <hip/hip_runtime.h>
#include <math.h>

// AugmentPipe: flip -> affine(rot/scale/trans) bilinear-reflect sample ->
// brightness -> contrast -> saturation -> cutout(noise). One fused pass.
// B=64, C=3, H=W=512, float32 in/out.
//
// R3 -> R4: R3's LDS staging regressed (309us, VALU 58%) because staging used
// runtime-width loops (ry*fw muls, flip selects, ~210 VALU/px) + stride-fw
// bank conflicts (4.2M cy). R4 keeps the staging concept but makes it cheap:
//   (1) 16x16 output tiles: affine footprint <= 1.2024*15*sqrt2+4 ~ 30 px
//       -> COMPILE-TIME 32-wide box, fh<=32. No runtime strides anywhere.
//   (2) LDS row stride 34: rotated gather (dy=1,dcol=+-1) -> bank delta
//       {1,3}, no 4-way conflicts in either rotation direction.
//   (3) Staging = flattened (tid>>5, tid&31), full 32-wide rows, row loop
//       only (r += 8): 1 coalesced global load + 1 ds_write per iteration.
//   (4) Box widened 1px each side for corner-vs-pixel fp slack; clamping
//       taps into the box == reference clip (clamped taps coincide, lerp
//       weight multiplies zero); reflect==clip valid for xx,yy in [-1,512].
//       True-reflection boundary blocks -> R2-style global-gather fallback
//       (block-uniform branch).

constexpr int Bn = 64;
constexpr int Cn = 3;
constexpr int Hn = 512;
constexpr int Wn = 512;
constexpr float TRANSLATE_STD = 0.125f;
constexpr float SCALE_STD = 0.2f;
constexpr int CUT_H = 256; // int(512*0.5)
constexpr int CUT_W = 256;

constexpr int FW = 32;       // staged box width (floats, fixed)
constexpr int FSTRIDE = 34;  // LDS row stride: rot gather bank-safe
constexpr int FH_MAX = 32;   // max staged rows (math bound ~30)
constexpr int CH_LDS = FSTRIDE * FH_MAX;  // 1088 floats/channel

typedef float f2v __attribute__((ext_vector_type(2)));

__device__ __forceinline__ f2v load2(const float* p) {
    f2v r;
    __builtin_memcpy(&r, p, 8);
    return r;
}

__device__ __forceinline__ float reflect_coord(float v, float size) {
    v = fabsf(v + 0.5f);
    v = fmodf(v, 2.0f * size);
    v = fminf(v, 2.0f * size - v);
    return fminf(fmaxf(v - 0.5f, 0.0f), size - 1.0f);
}

__global__ __launch_bounds__(256) void augment_kernel(
    const float* __restrict__ images,
    const float* __restrict__ u_angle,
    const float* __restrict__ u_scale,
    const float* __restrict__ u_trans,
    const float* __restrict__ u_bright,
    const float* __restrict__ u_contrast,
    const float* __restrict__ u_sat,
    const float* __restrict__ noise,
    const int* __restrict__ m_flip,
    const int* __restrict__ m_rot,
    const int* __restrict__ m_scale,
    const int* __restrict__ m_trans,
    const int* __restrict__ m_bright,
    const int* __restrict__ m_contrast,
    const int* __restrict__ m_sat,
    const int* __restrict__ m_cut,
    const int* __restrict__ y0p,
    const int* __restrict__ x0p,
    float* __restrict__ out)
{
    __shared__ float lds[Cn * CH_LDS];   // 13056 B -> 8 blocks/CU fits 160KB

    const int x = blockIdx.x * 16 + threadIdx.x;
    const int y = blockIdx.y * 16 + threadIdx.y;
    const int b = blockIdx.z;

    // Per-batch params — blockIdx.z-uniform => scalar loads.
    const float angle = (m_rot[b] > 0) ? (u_angle[b] * 2.0f - 1.0f) * 3.14159265358979323846f : 0.0f;
    const float sc    = (m_scale[b] > 0) ? (u_scale[b] * 2.0f - 1.0f) * SCALE_STD + 1.0f : 1.0f;
    const float tr    = (m_trans[b] > 0) ? (u_trans[b] * 2.0f - 1.0f) * TRANSLATE_STD : 0.0f;
    const float bb    = (m_bright[b] > 0) ? u_bright[b] * 0.2f : 0.0f;
    const float cc    = (m_contrast[b] > 0) ? u_contrast[b] + 0.5f : 1.0f;
    const float ss    = (m_sat[b] > 0) ? u_sat[b] * 2.0f : 1.0f;
    const bool  flip  = m_flip[b] > 0;
    const bool  docut = m_cut[b] > 0;
    const int   cy0   = y0p[b];
    const int   cx0   = x0p[b];

    float saf, caf;
    __sincosf(angle, &saf, &caf);

    // Same fp ops for pixels and corners; affine => tile min/max at corners.
    auto coord = [&](float fx, float fy, float& oxx, float& oyy) {
        const float gx0 = -1.0f + (2.0f / 511.0f) * fx;
        const float gy0 = -1.0f + (2.0f / 511.0f) * fy;
        const float gx = sc * (caf * gx0 - saf * gy0) + tr;
        const float gy = sc * (saf * gx0 + caf * gy0) + tr;
        oxx = ((gx + 1.0f) * (float)Wn - 1.0f) * 0.5f;
        oyy = ((gy + 1.0f) * (float)Hn - 1.0f) * 0.5f;
    };

    float xx, yy;
    coord((float)x, (float)y, xx, yy);

    const float tx0 = (float)(blockIdx.x * 16);
    const float tx1 = tx0 + 15.0f;
    const float ty0 = (float)(blockIdx.y * 16);
    const float ty1 = ty0 + 15.0f;
    float cxx0, cyy0, cxx1, cyy1, cxx2, cyy2, cxx3, cyy3;
    coord(tx0, ty0, cxx0, cyy0);
    coord(tx1, ty0, cxx1, cyy1);
    coord(tx0, ty1, cxx2, cyy2);
    coord(tx1, ty1, cxx3, cyy3);
    const float minxx = fminf(fminf(cxx0, cxx1), fminf(cxx2, cxx3));
    const float maxxx = fmaxf(fmaxf(cxx0, cxx1), fmaxf(cxx2, cxx3));
    const float minyy = fminf(fminf(cyy0, cyy1), fminf(cyy2, cyy3));
    const float maxyy = fmaxf(fmaxf(cyy0, cyy1), fmaxf(cyy2, cyy3));

    // reflect == clip for coords in [-1.0, 512.0]; margin for fp slack.
    bool staged = (minxx >= -0.9f) && (maxxx <= 511.9f) &&
                  (minyy >= -0.9f) && (maxyy <= 511.9f);

    int x_lo = 0, x_hi = 1, y_lo = 0, y_hi = 1, fh = 1;
    if (staged) {
        // 1px widening each side absorbs corner-vs-pixel fp rounding.
        x_lo = min(max((int)floorf(minxx) - 1, 0), Wn - FW);
        x_hi = x_lo + FW - 1;                       // <= 511 by construction
        y_lo = max((int)floorf(minyy) - 1, 0);
        y_hi = min((int)floorf(maxyy) + 2, Hn - 1);
        fh = y_hi - y_lo + 1;
        // Guards (mathematically unreachable; keep for safety).
        if (fh > FH_MAX || ((int)floorf(maxxx) + 1) > x_hi) staged = false;
    }

    const size_t plane = (size_t)Hn * Wn;
    const float* imgb = images + (size_t)b * Cn * plane;

    float vals[Cn];

    if (staged) {
        // ---- Stage: full 32-wide rows, coalesced; flip folded into source
        // column so gather uses unflipped box indices.
        const int tid = threadIdx.y * 16 + threadIdx.x;
        const int srx = tid & 31;
        const int sry = tid >> 5;                   // 0..7
        const int gcol = flip ? (Wn - 1 - (x_lo + srx)) : (x_lo + srx);
        #pragma unroll
        for (int c = 0; c < Cn; ++c) {
            const float* srcc = imgb + (size_t)c * plane + gcol;
            float* dstc = &lds[c * CH_LDS];
            for (int r = sry; r < fh; r += 8) {
                dstc[r * FSTRIDE + srx] = srcc[(size_t)(y_lo + r) * Wn];
            }
        }
        __syncthreads();

        // ---- Bilinear from LDS. Taps clamped into the box reproduce the
        // reference clip semantics exactly (clamped => taps coincide => the
        // out-of-range lerp weight multiplies zero).
        const float x0f = floorf(xx);
        const float y0f = floorf(yy);
        const float wx = xx - x0f;
        const float wy = yy - y0f;
        const int x0i = (int)x0f;
        const int y0i = (int)y0f;

        const int xa = min(max(x0i, x_lo), x_hi);
        const int xb = min(max(x0i + 1, x_lo), x_hi);
        const int pb = min(xa, x_hi - 1);           // pair base in [x_lo, x_hi-1]
        const bool s0 = (xa != pb);
        const bool s1 = (xb != pb);
        const int ya = min(max(y0i, y_lo), y_hi) - y_lo;
        const int yb = min(max(y0i + 1, y_lo), y_hi) - y_lo;
        const int col = pb - x_lo;
        const int off0 = ya * FSTRIDE + col;        // compile-time stride
        const int off1 = yb * FSTRIDE + col;

        #pragma unroll
        for (int c = 0; c < Cn; ++c) {
            const float* ch = &lds[c * CH_LDS];
            const float t0x = ch[off0], t0y = ch[off0 + 1];   // ds_read2_b32
            const float t1x = ch[off1], t1y = ch[off1 + 1];
            const float v00 = s0 ? t0y : t0x;
            const float v01 = s1 ? t0y : t0x;
            const float v10 = s0 ? t1y : t1x;
            const float v11 = s1 ? t1y : t1x;
            const float top = v00 + wx * (v01 - v00);
            const float bot = v10 + wx * (v11 - v10);
            float v = top + wy * (bot - top);
            v = fminf(fmaxf(v + bb, -1.0f), 1.0f);   // brightness + clip
            v = fminf(fmaxf(v * cc, -1.0f), 1.0f);   // contrast + clip
            vals[c] = v;
        }
    } else {
        // ---- Fallback: direct global gather with true reflect (boundary
        // blocks of transformed batches). Identical math to the R2 kernel.
        const float rxx = reflect_coord(xx, (float)Wn);
        const float ryy = reflect_coord(yy, (float)Hn);

        const float x0f = floorf(rxx);
        const float y0f = floorf(ryy);
        const float wx = rxx - x0f;
        const float wy = ryy - y0f;

        int x0i = (int)fminf(fmaxf(x0f, 0.0f), (float)(Wn - 1));
        int x1i = (int)fminf(x0f + 1.0f, (float)(Wn - 1));
        const int y0i = (int)fminf(fmaxf(y0f, 0.0f), (float)(Hn - 1));
        const int y1i = (int)fminf(y0f + 1.0f, (float)(Hn - 1));

        if (flip) { x0i = (Wn - 1) - x0i; x1i = (Wn - 1) - x1i; }

        const int xbase = min(min(x0i, x1i), Wn - 2);
        const bool s0 = (x0i != xbase);
        const bool s1 = (x1i != xbase);

        const int r0 = y0i * Wn + xbase;
        const int r1 = y1i * Wn + xbase;

        #pragma unroll
        for (int c = 0; c < Cn; ++c) {
            const float* p = imgb + (size_t)c * plane;
            const f2v t0 = load2(p + r0);
            const f2v t1 = load2(p + r1);
            const float v00 = s0 ? t0.y : t0.x;
            const float v01 = s1 ? t0.y : t0.x;
            const float v10 = s0 ? t1.y : t1.x;
            const float v11 = s1 ? t1.y : t1.x;
            const float top = v00 + wx * (v01 - v00);
            const float bot = v10 + wx * (v11 - v10);
            float v = top + wy * (bot - top);
            v = fminf(fmaxf(v + bb, -1.0f), 1.0f);
            v = fminf(fmaxf(v * cc, -1.0f), 1.0f);
            vals[c] = v;
        }
    }

    const float gray = (vals[0] + vals[1] + vals[2]) * (1.0f / 3.0f);
    const bool cut = docut && (y >= cy0) && (y < cy0 + CUT_H) && (x >= cx0) && (x < cx0 + CUT_W);

    const size_t base = (size_t)b * Cn * plane + (size_t)y * Wn + (size_t)x;
    #pragma unroll
    for (int c = 0; c < Cn; ++c) {
        float v = gray + ss * (vals[c] - gray);
        v = fminf(fmaxf(v, -1.0f), 1.0f);
        if (cut) v = __builtin_nontemporal_load(&noise[base + c * plane]);
        __builtin_nontemporal_store(v, &out[base + c * plane]);
    }
}

extern "C" void kernel_launch(void* const* d_in, const int* in_sizes, int n_in,
                              void* d_out, int out_size, void* d_ws, size_t ws_size,
                              hipStream_t stream) {
    const float* images     = (const float*)d_in[0];
    const float* u_angle    = (const float*)d_in[1];
    const float* u_scale    = (const float*)d_in[2];
    const float* u_trans    = (const float*)d_in[3];
    const float* u_bright   = (const float*)d_in[4];
    const float* u_contrast = (const float*)d_in[5];
    const float* u_sat      = (const float*)d_in[6];
    const float* noise      = (const float*)d_in[7];
    const int*   m_flip     = (const int*)d_in[8];
    const int*   m_rot      = (const int*)d_in[9];
    const int*   m_scale    = (const int*)d_in[10];
    const int*   m_trans    = (const int*)d_in[11];
    const int*   m_bright   = (const int*)d_in[12];
    const int*   m_contrast = (const int*)d_in[13];
    const int*   m_sat      = (const int*)d_in[14];
    const int*   m_cut      = (const int*)d_in[15];
    const int*   y0p        = (const int*)d_in[16];
    const int*   x0p        = (const int*)d_in[17];
    float* out = (float*)d_out;

    dim3 block(16, 16);
    dim3 grid(Wn / 16, Hn / 16, Bn);
    augment_kernel<<<grid, block, 0, stream>>>(
        images, u_angle, u_scale, u_trans, u_bright, u_contrast, u_sat, noise,
        m_flip, m_rot, m_scale, m_trans, m_bright, m_contrast, m_sat, m_cut,
        y0p, x0p, out);
}

// Round 3
// 507.902 us; speedup vs baseline: 1.2483x; 1.1606x over previous
//
#include <hip/hip_runtime.h>
#include <math.h>

// AugmentPipe: flip -> affine(rot/scale/trans) bilinear-reflect sample ->
// brightness -> contrast -> saturation -> cutout(noise). One fused pass.
// B=64, C=3, H=W=512, float32 in/out.
//
// R4 -> R5 (R4: 264us, VALU 52%, FETCH 344MB, 7M LDS-conflict cy):
//   (1) Box from ONE corner + affine deltas (affine => extrema at corners;
//       +-1px box slack absorbs fp diff) — kills the 4x per-thread corner
//       chain (~60 VALU -> ~16).
//   (2) INTERIOR-only staged path (minxx>=1 && maxxx<=509, same y): taps
//       provably in-box, in-image => no clamps, no selects, no reflect —
//       exact bilinear. Edge ring (~12% of blocks) -> R2 direct gather with
//       true reflect (also covers reflecting blocks).
//   (3) Staging: 2 unrolled shots of 16 rows (8B/lane), all 6 global loads
//       issued before the 6 ds_write_b64 (1 HBM latency, not 9); no loop
//       address arithmetic.
//   (4) LDS stride 40 ( == 8 mod 32): for the 16x4 wave shape bank =
//       x + 8*y mod 32 -> exactly 2 lanes/bank on gather AND staging = free.
//       (R4's stride 34 gave 4-way.) 160B rows, 16B aligned.
//   (5) XCD-chunk swizzle (65536 blocks % 8 == 0 -> bijective): each XCD
//       gets 8 contiguous batches; vertical halo re-reads hit its L2
//       (reuse distance 32 blocks ~ 256KB << 4MB).

constexpr int Bn = 64;
constexpr int Cn = 3;
constexpr int Hn = 512;
constexpr int Wn = 512;
constexpr float TRANSLATE_STD = 0.125f;
constexpr float SCALE_STD = 0.2f;
constexpr int CUT_H = 256; // int(512*0.5)
constexpr int CUT_W = 256;

constexpr int FW = 32;        // staged box width (floats)
constexpr int FSTRIDE = 40;   // LDS row stride; 40 % 32 == 8 -> conflict-free
constexpr int FH_MAX = 32;    // staged rows capacity (math bound ~30)
constexpr int CH_LDS = FSTRIDE * FH_MAX;   // 1280 floats per channel

typedef float f2v __attribute__((ext_vector_type(2)));

__device__ __forceinline__ f2v load2(const float* p) {
    f2v r;
    __builtin_memcpy(&r, p, 8);
    return r;
}

__device__ __forceinline__ float reflect_coord(float v, float size) {
    v = fabsf(v + 0.5f);
    v = fmodf(v, 2.0f * size);
    v = fminf(v, 2.0f * size - v);
    return fminf(fmaxf(v - 0.5f, 0.0f), size - 1.0f);
}

__global__ __launch_bounds__(256) void augment_kernel(
    const float* __restrict__ images,
    const float* __restrict__ u_angle,
    const float* __restrict__ u_scale,
    const float* __restrict__ u_trans,
    const float* __restrict__ u_bright,
    const float* __restrict__ u_contrast,
    const float* __restrict__ u_sat,
    const float* __restrict__ noise,
    const int* __restrict__ m_flip,
    const int* __restrict__ m_rot,
    const int* __restrict__ m_scale,
    const int* __restrict__ m_trans,
    const int* __restrict__ m_bright,
    const int* __restrict__ m_contrast,
    const int* __restrict__ m_sat,
    const int* __restrict__ m_cut,
    const int* __restrict__ y0p,
    const int* __restrict__ x0p,
    float* __restrict__ out)
{
    __shared__ __align__(16) float lds[Cn * CH_LDS];   // 15360 B

    // XCD-chunk swizzle: dispatch order is blockIdx.x fastest; each XCD
    // (orig % 8) gets a contiguous 8192-block chunk = 8 whole batches,
    // x-fastest within a batch.
    const int lin = blockIdx.x + (blockIdx.y << 5) + (blockIdx.z << 10);
    const int swz = ((lin & 7) << 13) + (lin >> 3);
    const int tx16 = (swz & 31) << 4;          // tile origin x
    const int ty16 = ((swz >> 5) & 31) << 4;   // tile origin y
    const int b    = swz >> 10;

    const int x = tx16 + threadIdx.x;
    const int y = ty16 + threadIdx.y;

    // Per-batch params — uniform per block.
    const float angle = (m_rot[b] > 0) ? (u_angle[b] * 2.0f - 1.0f) * 3.14159265358979323846f : 0.0f;
    const float sc    = (m_scale[b] > 0) ? (u_scale[b] * 2.0f - 1.0f) * SCALE_STD + 1.0f : 1.0f;
    const float tr    = (m_trans[b] > 0) ? (u_trans[b] * 2.0f - 1.0f) * TRANSLATE_STD : 0.0f;
    const float bb    = (m_bright[b] > 0) ? u_bright[b] * 0.2f : 0.0f;
    const float cc    = (m_contrast[b] > 0) ? u_contrast[b] + 0.5f : 1.0f;
    const float ss    = (m_sat[b] > 0) ? u_sat[b] * 2.0f : 1.0f;
    const bool  flip  = m_flip[b] > 0;
    const bool  docut = m_cut[b] > 0;
    const int   cy0   = y0p[b];
    const int   cx0   = x0p[b];

    float saf, caf;
    __sincosf(angle, &saf, &caf);

    // Per-pixel source coordinate — op chain identical to harness-passed R2/R4.
    auto coord = [&](float fx, float fy, float& oxx, float& oyy) {
        const float gx0 = -1.0f + (2.0f / 511.0f) * fx;
        const float gy0 = -1.0f + (2.0f / 511.0f) * fy;
        const float gx = sc * (caf * gx0 - saf * gy0) + tr;
        const float gy = sc * (saf * gx0 + caf * gy0) + tr;
        oxx = ((gx + 1.0f) * (float)Wn - 1.0f) * 0.5f;
        oyy = ((gy + 1.0f) * (float)Hn - 1.0f) * 0.5f;
    };

    float xx, yy;
    coord((float)x, (float)y, xx, yy);

    // Tile bbox: origin corner (full chain) + affine deltas. d/dx,d/dy of the
    // source coord are +-sc*{caf,saf}*(512/511). +-1px slack covers fp diff.
    float xx00, yy00;
    coord((float)tx16, (float)ty16, xx00, yy00);
    const float k  = sc * (512.0f / 511.0f);
    const float px = caf * k * 15.0f;   // d(xx) over 15 output cols
    const float qx = -saf * k * 15.0f;  // d(xx) over 15 output rows
    const float py = saf * k * 15.0f;
    const float qy = caf * k * 15.0f;
    const float minxx = xx00 + fminf(px, 0.0f) + fminf(qx, 0.0f);
    const float maxxx = xx00 + fmaxf(px, 0.0f) + fmaxf(qx, 0.0f);
    const float minyy = yy00 + fminf(py, 0.0f) + fminf(qy, 0.0f);
    const float maxyy = yy00 + fmaxf(py, 0.0f) + fmaxf(qy, 0.0f);

    // Interior gate: taps (floor-1 .. floor+2) all inside [0,511] => no
    // reflection, no clamping anywhere. Block-uniform.
    bool interior = (minxx >= 1.0f) && (maxxx <= 509.0f) &&
                    (minyy >= 1.0f) && (maxyy <= 509.0f);

    int x_lo = 0, y_lo = 0, fh = 0;
    if (interior) {
        x_lo = min((int)minxx - 1, Wn - FW);     // truncation == floor (>=0)
        y_lo = (int)minyy - 1;
        fh = ((int)maxyy + 2) - y_lo + 1;        // rows to stage (<=30 by math)
        if (fh > FH_MAX) interior = false;       // unreachable; safety
    }

    const size_t plane = (size_t)Hn * Wn;
    const float* imgb = images + (size_t)b * Cn * plane;

    float vals[Cn];

    if (interior) {
        // ---- Stage fh rows x 32 cols, 3 channels. 8B/lane, 16 rows/shot,
        // 2 shots, fully unrolled: 6 loads in flight, then 6 ds_write_b64.
        const int tid = threadIdx.y * 16 + threadIdx.x;
        const int k2  = (tid & 15) * 2;          // pair column 0..30
        const int sry = tid >> 4;                // row 0..15
        const int scol = flip ? (Wn - 2 - (x_lo + k2)) : (x_lo + k2);
        const float* sp = imgb + (size_t)(y_lo + sry) * Wn + scol;
        const bool p1 = sry < fh;
        const bool p2 = sry + 16 < fh;

        f2v va0{}, vb0{}, vc0{}, va1{}, vb1{}, vc1{};
        if (p1) {
            va0 = load2(sp);
            vb0 = load2(sp + plane);
            vc0 = load2(sp + 2 * plane);
        }
        if (p2) {
            const float* sp2 = sp + 16 * Wn;
            va1 = load2(sp2);
            vb1 = load2(sp2 + plane);
            vc1 = load2(sp2 + 2 * plane);
        }
        if (flip) {   // reversed pair: swap halves
            f2v t;
            t = va0; va0.x = t.y; va0.y = t.x;
            t = vb0; vb0.x = t.y; vb0.y = t.x;
            t = vc0; vc0.x = t.y; vc0.y = t.x;
            t = va1; va1.x = t.y; va1.y = t.x;
            t = vb1; vb1.x = t.y; vb1.y = t.x;
            t = vc1; vc1.x = t.y; vc1.y = t.x;
        }
        float* dst = &lds[sry * FSTRIDE + k2];
        if (p1) {
            *(f2v*)(dst)              = va0;
            *(f2v*)(dst + CH_LDS)     = vb0;
            *(f2v*)(dst + 2 * CH_LDS) = vc0;
        }
        if (p2) {
            *(f2v*)(dst + 16 * FSTRIDE)              = va1;
            *(f2v*)(dst + CH_LDS + 16 * FSTRIDE)     = vb1;
            *(f2v*)(dst + 2 * CH_LDS + 16 * FSTRIDE) = vc1;
        }
        __syncthreads();

        // ---- Exact bilinear from LDS: no clamps (interior), no selects.
        const float fx = xx - (float)x_lo;       // >= ~1, <= ~31
        const float fy = yy - (float)y_lo;
        const int xi = (int)fx;
        const int yi = (int)fy;
        const float wx = fx - (float)xi;
        const float wy = fy - (float)yi;
        const float* ph = &lds[yi * FSTRIDE + xi];

        #pragma unroll
        for (int c = 0; c < Cn; ++c) {
            const float v00 = ph[0];
            const float v01 = ph[1];
            const float v10 = ph[FSTRIDE];
            const float v11 = ph[FSTRIDE + 1];
            ph += CH_LDS;
            const float top = v00 + wx * (v01 - v00);
            const float bot = v10 + wx * (v11 - v10);
            float v = top + wy * (bot - top);
            v = fminf(fmaxf(v + bb, -1.0f), 1.0f);   // brightness + clip
            v = fminf(fmaxf(v * cc, -1.0f), 1.0f);   // contrast + clip
            vals[c] = v;
        }
    } else {
        // ---- Edge/reflecting blocks (~12%): direct global gather with true
        // reflect. Identical math to the harness-passed R2 kernel.
        const float rxx = reflect_coord(xx, (float)Wn);
        const float ryy = reflect_coord(yy, (float)Hn);

        const float x0f = floorf(rxx);
        const float y0f = floorf(ryy);
        const float wx = rxx - x0f;
        const float wy = ryy - y0f;

        int x0i = (int)fminf(fmaxf(x0f, 0.0f), (float)(Wn - 1));
        int x1i = (int)fminf(x0f + 1.0f, (float)(Wn - 1));
        const int y0i = (int)fminf(fmaxf(y0f, 0.0f), (float)(Hn - 1));
        const int y1i = (int)fminf(y0f + 1.0f, (float)(Hn - 1));

        if (flip) { x0i = (Wn - 1) - x0i; x1i = (Wn - 1) - x1i; }

        const int xbase = min(min(x0i, x1i), Wn - 2);
        const bool s0 = (x0i != xbase);
        const bool s1 = (x1i != xbase);

        const int r0 = y0i * Wn + xbase;
        const int r1 = y1i * Wn + xbase;

        #pragma unroll
        for (int c = 0; c < Cn; ++c) {
            const float* p = imgb + (size_t)c * plane;
            const f2v t0 = load2(p + r0);
            const f2v t1 = load2(p + r1);
            const float v00 = s0 ? t0.y : t0.x;
            const float v01 = s1 ? t0.y : t0.x;
            const float v10 = s0 ? t1.y : t1.x;
            const float v11 = s1 ? t1.y : t1.x;
            const float top = v00 + wx * (v01 - v00);
            const float bot = v10 + wx * (v11 - v10);
            float v = top + wy * (bot - top);
            v = fminf(fmaxf(v + bb, -1.0f), 1.0f);
            v = fminf(fmaxf(v * cc, -1.0f), 1.0f);
            vals[c] = v;
        }
    }

    const float gray = (vals[0] + vals[1] + vals[2]) * (1.0f / 3.0f);
    const bool cut = docut && (y >= cy0) && (y < cy0 + CUT_H) && (x >= cx0) && (x < cx0 + CUT_W);

    const size_t base = (size_t)b * Cn * plane + (size_t)y * Wn + (size_t)x;
    #pragma unroll
    for (int c = 0; c < Cn; ++c) {
        float v = gray + ss * (vals[c] - gray);
        v = fminf(fmaxf(v, -1.0f), 1.0f);
        if (cut) v = __builtin_nontemporal_load(&noise[base + c * plane]);
        __builtin_nontemporal_store(v, &out[base + c * plane]);
    }
}

extern "C" void kernel_launch(void* const* d_in, const int* in_sizes, int n_in,
                              void* d_out, int out_size, void* d_ws, size_t ws_size,
                              hipStream_t stream) {
    const float* images     = (const float*)d_in[0];
    const float* u_angle    = (const float*)d_in[1];
    const float* u_scale    = (const float*)d_in[2];
    const float* u_trans    = (const float*)d_in[3];
    const float* u_bright   = (const float*)d_in[4];
    const float* u_contrast = (const float*)d_in[5];
    const float* u_sat      = (const float*)d_in[6];
    const float* noise      = (const float*)d_in[7];
    const int*   m_flip     = (const int*)d_in[8];
    const int*   m_rot      = (const int*)d_in[9];
    const int*   m_scale    = (const int*)d_in[10];
    const int*   m_trans    = (const int*)d_in[11];
    const int*   m_bright   = (const int*)d_in[12];
    const int*   m_contrast = (const int*)d_in[13];
    const int*   m_sat      = (const int*)d_in[14];
    const int*   m_cut      = (const int*)d_in[15];
    const int*   y0p        = (const int*)d_in[16];
    const int*   x0p        = (const int*)d_in[17];
    float* out = (float*)d_out;

    dim3 block(16, 16);
    dim3 grid(Wn / 16, Hn / 16, Bn);
    augment_kernel<<<grid, block, 0, stream>>>(
        images, u_angle, u_scale, u_trans, u_bright, u_contrast, u_sat, noise,
        m_flip, m_rot, m_scale, m_trans, m_bright, m_contrast, m_sat, m_cut,
        y0p, x0p, out);
}